// Round 5
// baseline (99415.674 us; speedup 1.0000x reference)
//
#include <hip/hip_runtime.h>
#include <math.h>

// Problem constants (fixed by the reference)
#define NB     16       // batch
#define NW     64       // net width W
#define NK     1024     // number of vis blocks
#define NPX    1024     // NPIX
#define NVIS_  65536
#define MEMB   8        // WGs per batch group
#define PXM    128      // pixels per member
#define TPB    256
#define NWG    128      // total workgroups

#define AG_LDF(p)    __hip_atomic_load((p), __ATOMIC_RELAXED, __HIP_MEMORY_SCOPE_AGENT)
#define AG_STF(p,v)  __hip_atomic_store((p), (v), __ATOMIC_RELAXED, __HIP_MEMORY_SCOPE_AGENT)
#define AG_LDU(p)    __hip_atomic_load((p), __ATOMIC_RELAXED, __HIP_MEMORY_SCOPE_AGENT)
#define AG_LD64(p)   __hip_atomic_load((p), __ATOMIC_RELAXED, __HIP_MEMORY_SCOPE_AGENT)
#define AG_ST64(p,v) __hip_atomic_store((p), (v), __ATOMIC_RELAXED, __HIP_MEMORY_SCOPE_AGENT)

// ws layout (32-bit words):
//   0           : global barrier root
//   32*(x+1)    : global barrier leaves, x=0..7 (per XCD slot)
//   288..303    : per-iteration global-max slots (float bits)
//   512..639    : tags [NB][MEMB] (monotonic step ordinals)
//   1024        : part [2][NB][MEMB][NW] ulong   (128 KB)
//   36864       : x0p  [NWG][NB][PXM][2] f32     (2 MB)
//   589824      : tau  [NB][NK][NW] f32          (4 MB)
#define WS_GMAX  288
#define WS_TAGS  512
#define WS_PART  1024
#define WS_X0P   36864
#define WS_TAU   589824

__global__ void robbi_init(unsigned* ws) {
  for (int i = threadIdx.x; i < 1024; i += blockDim.x)
    __hip_atomic_store(ws + i, 0u, __ATOMIC_RELAXED, __HIP_MEMORY_SCOPE_AGENT);
}

// Global barrier (x0 handoff + per-iteration threshold only — 11 uses total).
__device__ __forceinline__ void gbar_all(unsigned* root, unsigned* leaf, unsigned n) {
  __syncthreads();
  if (threadIdx.x == 0) {
    unsigned old = __hip_atomic_fetch_add(leaf, 1u, __ATOMIC_ACQ_REL, __HIP_MEMORY_SCOPE_AGENT);
    if ((old & 15u) == 15u)
      __hip_atomic_fetch_add(root, 1u, __ATOMIC_ACQ_REL, __HIP_MEMORY_SCOPE_AGENT);
    const unsigned target = 8u * n;
    while (__hip_atomic_load(root, __ATOMIC_ACQUIRE, __HIP_MEMORY_SCOPE_AGENT) < target)
      __builtin_amdgcn_s_sleep(4);
  }
  __syncthreads();
}

// One Gauss-Seidel step. HRC/HIC = current H tile (regs), HRN/HIN = prefetch slot.
// Sync: wave0 posts 64 packed partials (relaxed-agent 8B) -> RELEASE tag store
// (vmcnt(0) wave-wide orders data before tag) -> relaxed poll of 8 tags ->
// ONE acquire fence -> fan-in loads. No RMW, no per-poll invalidates.
// All macro-locals end in '_' (R3 lesson: KARG may reference caller's loop var).
#define STEP_BODY(KARG, HRC, HIC, HRN, HIN)                                    \
  {                                                                            \
    const int k_ = (KARG);                                                     \
    const int buf_ = k_ & 1;                                                   \
    const unsigned tgt_ = (unsigned)(iter * NK + k_ + 1);                      \
    /* ---- phase A: zpart[w] = sum_{4 px} x*conj(H) (regs+LDS only) ---- */   \
    float4 xq0_ = *(const float4*)&xs[p4 * 2];                                 \
    float4 xq1_ = *(const float4*)&xs[p4 * 2 + 4];                             \
    float zpr_[8], zpi_[8];                                                    \
    _Pragma("unroll")                                                          \
    for (int i = 0; i < 8; ++i) {                                              \
      float zr = xq0_.x * HRC[i].x + xq0_.y * HIC[i].x                         \
               + xq0_.z * HRC[i].y + xq0_.w * HIC[i].y                         \
               + xq1_.x * HRC[i].z + xq1_.y * HIC[i].z                         \
               + xq1_.z * HRC[i].w + xq1_.w * HIC[i].w;                        \
      float zi = xq0_.y * HRC[i].x - xq0_.x * HIC[i].x                         \
               + xq0_.w * HRC[i].y - xq0_.z * HIC[i].y                         \
               + xq1_.y * HRC[i].z - xq1_.x * HIC[i].z                         \
               + xq1_.w * HRC[i].w - xq1_.z * HIC[i].w;                        \
      _Pragma("unroll")                                                        \
      for (int msk = 16; msk >= 1; msk >>= 1) {                                \
        zr += __shfl_xor(zr, msk); zi += __shfl_xor(zi, msk);                  \
      }                                                                        \
      zpr_[i] = zr; zpi_[i] = zi;                                              \
    }                                                                          \
    if (g5 == 0) {                                                             \
      _Pragma("unroll")                                                        \
      for (int i = 0; i < 8; ++i)                                              \
        partlds[8 * i + wsub] = make_float2(zpr_[i], zpi_[i]);                 \
    }                                                                          \
    asm volatile("s_waitcnt lgkmcnt(0)" ::: "memory");                         \
    __builtin_amdgcn_s_barrier(); /* B1: partlds ready (no vmcnt drain) */     \
    asm volatile("" ::: "memory");                                             \
    /* ---- wave0: post data (64x 8B) + RELEASE tag ---- */                    \
    if (t < 64) {                                                              \
      union { float2 f2; unsigned long long u; } cv_;                          \
      cv_.f2 = partlds[t];                                                     \
      AG_ST64(part64 + (size_t)(((buf_ * NB + b) * MEMB + m) * NW + t), cv_.u);\
    }                                                                          \
    if (t == 0)                                                                \
      __hip_atomic_store(tags + m, tgt_, __ATOMIC_RELEASE,                     \
                         __HIP_MEMORY_SCOPE_AGENT);                            \
    asm volatile("" ::: "memory"); /* keep prefetch below the release */       \
    /* ---- all waves: prefetch H for k_+1 (in flight across barriers) ---- */ \
    {                                                                          \
      const int kn_ = (k_ + 1 < NK) ? (k_ + 1) : 0;                            \
      const size_t rbn_ = (size_t)(kn_ * NW + wsub) * NPX + m * PXM + p4;      \
      _Pragma("unroll")                                                        \
      for (int i = 0; i < 8; ++i) {                                            \
        HRN[i] = *(const float4*)(H_re + rbn_ + (size_t)i * 8 * NPX);          \
        HIN[i] = *(const float4*)(H_im + rbn_ + (size_t)i * 8 * NPX);          \
      }                                                                        \
    }                                                                          \
    /* ---- wave0: relaxed poll -> one acquire fence -> fan-in + MLP ---- */   \
    if (t < 64) {                                                              \
      for (;;) {                                                               \
        unsigned tv_ = 0xFFFFFFFFu;                                            \
        if (t < MEMB) tv_ = AG_LDU(tags + t);                                  \
        if (__all((int)(tv_ >= tgt_))) break;                                  \
      }                                                                        \
      __builtin_amdgcn_fence(__ATOMIC_ACQUIRE, "agent");                       \
      float zr = 0.f, zi = 0.f;                                                \
      _Pragma("unroll")                                                        \
      for (int mm = 0; mm < MEMB; ++mm) {                                      \
        union { float2 f2; unsigned long long u; } dv_;                        \
        dv_.u = AG_LD64(part64 + (size_t)(((buf_ * NB + b) * MEMB + mm) * NW + t)); \
        zr += dv_.f2.x; zi += dv_.f2.y;                                        \
      }                                                                        \
      float tpe_ = (iter == 0) ? 0.f : tpr;                                    \
      float dr_ = ypr_r - zr, di_ = ypr_i - zi;                                \
      r2s[t] = dr_ * dr_ + di_ * di_;                                          \
      tpl[t] = tpe_;                                                           \
      float e_ = bE[t];                                                        \
      _Pragma("unroll 16")                                                     \
      for (int j = 0; j < 64; ++j) e_ += wE[t * 65 + j] * r2s[j];              \
      hts[t] = 1.f / (1.f + __expf(-e_));                                      \
      float a_ = bU[t] + bM[t];                                                \
      _Pragma("unroll 16")                                                     \
      for (int j = 0; j < 64; ++j)                                             \
        a_ += wU[t * 65 + j] * hts[j] + wM[t * 65 + j] * tpl[j];               \
      float wn_ = fmaxf(a_, 0.f);                                              \
      if (m == 0) AG_STF(tau + (size_t)(b * NK + k_) * NW + t, wn_);           \
      rs[2 * t] = ypr_r - zr * wn_; rs[2 * t + 1] = ypr_i - zi * wn_;          \
      /* prefetch y/tau for next step (regs, waited at use) */                 \
      const int kn_ = (k_ + 1 < NK) ? (k_ + 1) : 0;                            \
      ypr_r = y_re[b * NVIS_ + kn_ * NW + t];                                  \
      ypr_i = y_im[b * NVIS_ + kn_ * NW + t];                                  \
      tpr = AG_LDF(tau + (size_t)(b * NK + kn_) * NW + t);                     \
    }                                                                          \
    /* ---- B2: rs visible to all waves (no vmcnt drain) ---- */               \
    asm volatile("s_waitcnt lgkmcnt(0)" ::: "memory");                         \
    __builtin_amdgcn_s_barrier();                                              \
    asm volatile("" ::: "memory");                                             \
    /* ---- phase C: x[px] += (1/W) * sum_w r[w]*H[w,px] (H from regs) ---- */ \
    {                                                                          \
      float cr0 = 0.f, ci0 = 0.f, cr1 = 0.f, ci1 = 0.f;                        \
      float cr2 = 0.f, ci2 = 0.f, cr3 = 0.f, ci3 = 0.f;                        \
      _Pragma("unroll")                                                        \
      for (int i = 0; i < 8; ++i) {                                            \
        float rr = rs[(8 * i + wsub) * 2], ri = rs[(8 * i + wsub) * 2 + 1];    \
        cr0 += rr * HRC[i].x - ri * HIC[i].x; ci0 += rr * HIC[i].x + ri * HRC[i].x; \
        cr1 += rr * HRC[i].y - ri * HIC[i].y; ci1 += rr * HIC[i].y + ri * HRC[i].y; \
        cr2 += rr * HRC[i].z - ri * HIC[i].z; ci2 += rr * HIC[i].z + ri * HRC[i].z; \
        cr3 += rr * HRC[i].w - ri * HIC[i].w; ci3 += rr * HIC[i].w + ri * HRC[i].w; \
      }                                                                        \
      float4* r8_ = (float4*)red8;                                             \
      r8_[(wsub * 32 + g5) * 2]     = make_float4(cr0, ci0, cr1, ci1);         \
      r8_[(wsub * 32 + g5) * 2 + 1] = make_float4(cr2, ci2, cr3, ci3);         \
      asm volatile("s_waitcnt lgkmcnt(0)" ::: "memory");                       \
      __builtin_amdgcn_s_barrier(); /* B3: red8 ready */                       \
      asm volatile("" ::: "memory");                                           \
      int p_ = t & 127, c_ = t >> 7;                                           \
      float ssum_ = 0.f;                                                       \
      _Pragma("unroll")                                                        \
      for (int w2 = 0; w2 < 8; ++w2)                                           \
        ssum_ += red8[(w2 * 32 + (p_ >> 2)) * 8 + (p_ & 3) * 2 + c_];          \
      xs[p_ * 2 + c_] += ssum_ * (1.f / NW);                                   \
      asm volatile("s_waitcnt lgkmcnt(0)" ::: "memory");                       \
      __builtin_amdgcn_s_barrier(); /* B4: xs settled for next phase A */      \
      asm volatile("" ::: "memory");                                           \
    }                                                                          \
  }

__global__ __launch_bounds__(TPB) void robbi_persistent(
    const float* __restrict__ y_re, const float* __restrict__ y_im,
    const float* __restrict__ H_re, const float* __restrict__ H_im,
    const float* __restrict__ Ew, const float* __restrict__ Eb,
    const float* __restrict__ Uw, const float* __restrict__ Ub,
    const float* __restrict__ Mw, const float* __restrict__ Mb,
    const float* __restrict__ thr_p, const int* __restrict__ niter_p,
    float* __restrict__ out, float* ws) {
  const int bid = blockIdx.x;
  const int t = threadIdx.x;
  // 8 members of a batch group share blockIdx % 8 (same-XCD under round-robin)
  const int xcd = bid & 7, gi = bid >> 3;
  const int b = xcd + 8 * (gi >> 3);   // batch 0..15
  const int m = gi & 7;                // member 0..7

  unsigned* wsu   = (unsigned*)ws;
  unsigned* root  = wsu;
  unsigned* leaf  = wsu + 32 * (xcd + 1);
  unsigned* gmax  = wsu + WS_GMAX;
  unsigned* tags  = wsu + WS_TAGS + b * MEMB;
  unsigned long long* part64 = (unsigned long long*)(ws + WS_PART);
  float* x0p  = ws + WS_X0P;
  float* tau  = ws + WS_TAU;

  __shared__ float wE[NW * 65], wU[NW * 65], wM[NW * 65];
  __shared__ float bE[NW], bU[NW], bM[NW];
  __shared__ float xs[PXM * 2];
  __shared__ float r2s[NW], tpl[NW], hts[NW];
  __shared__ float rs[2 * NW];
  __shared__ float2 partlds[NW];
  __shared__ float red8[2048];
  __shared__ float ysr[2048], ysi[2048];
  __shared__ float axs[PXM];

  const float thr = *thr_p;
  const int niter = *niter_p;

  // ---- cache MLP weights (row-padded 65 -> conflict-free row reads) ----
  for (int i = t; i < NW * NW; i += TPB) {
    int r = i >> 6, c = i & 63;
    wE[r * 65 + c] = Ew[i]; wU[r * 65 + c] = Uw[i]; wM[r * 65 + c] = Mw[i];
  }
  if (t < NW) { bE[t] = Eb[t]; bU[t] = Ub[t]; bM[t] = Mb[t]; }

  const int wsub = t >> 5;        // 0..7
  const int g5   = t & 31;        // 0..31
  const int p4   = 4 * g5;        // pixel quad base within 128-px slice

  // ---- x0 stage 1: non-redundant partial GEMM over (kw-chunk, pixel-slice) ----
  {
    const int kwc = bid >> 3, ps = bid & 7;
    float ar[2][4], ai[2][4];
#pragma unroll
    for (int h = 0; h < 2; ++h)
#pragma unroll
      for (int j = 0; j < 4; ++j) { ar[h][j] = 0.f; ai[h][j] = 0.f; }
    for (int slab = 0; slab < 32; ++slab) {
      const int kw0 = kwc * 4096 + slab * 128;
      for (int e = t; e < 2048; e += TPB) {
        int bb = e >> 7, j = e & 127;
        ysr[e] = y_re[bb * NVIS_ + kw0 + j];
        ysi[e] = y_im[bb * NVIS_ + kw0 + j];
      }
      __syncthreads();
      for (int j = 0; j < 128; ++j) {
        const size_t off = (size_t)(kw0 + j) * NPX + ps * PXM + p4;
        float4 h4r = *(const float4*)(H_re + off);
        float4 h4i = *(const float4*)(H_im + off);
#pragma unroll
        for (int h = 0; h < 2; ++h) {
          int bb = wsub + 8 * h;
          float yr = ysr[bb * 128 + j], yi = ysi[bb * 128 + j];
          ar[h][0] += yr * h4r.x - yi * h4i.x; ai[h][0] += yr * h4i.x + yi * h4r.x;
          ar[h][1] += yr * h4r.y - yi * h4i.y; ai[h][1] += yr * h4i.y + yi * h4r.y;
          ar[h][2] += yr * h4r.z - yi * h4i.z; ai[h][2] += yr * h4i.z + yi * h4r.z;
          ar[h][3] += yr * h4r.w - yi * h4i.w; ai[h][3] += yr * h4i.w + yi * h4r.w;
        }
      }
      __syncthreads();
    }
#pragma unroll
    for (int h = 0; h < 2; ++h) {
      int bb = wsub + 8 * h;
#pragma unroll
      for (int j = 0; j < 4; ++j) {
        float* pp = x0p + ((size_t)(bid * NB + bb) * PXM + p4 + j) * 2;
        AG_STF(pp, ar[h][j]); AG_STF(pp + 1, ai[h][j]);
      }
    }
  }
  gbar_all(root, leaf, 1);

  // ---- x0 stage 2: reduce the 16 kw-chunks for this member's slice ----
  {
    int p = t & 127, c = t >> 7;
    float s = 0.f;
    for (int kwc = 0; kwc < 16; ++kwc)
      s += AG_LDF(x0p + ((size_t)((kwc * 8 + m) * NB + b) * PXM + p) * 2 + c);
    xs[p * 2 + c] = s;
  }
  __syncthreads();

  if (niter <= 0) {
    if (t < PXM) {
      float xr = xs[2 * t], xi = xs[2 * t + 1];
      out[b * NPX + m * PXM + t] = sqrtf(xr * xr + xi * xi);
    }
    return;
  }

  // ---- prologue: H tile for k=0 into slot A; y/tau prefetch for k=0 ----
  float4 hrA[8], hiA[8], hrB[8], hiB[8];
  {
    const size_t rb0 = (size_t)(0 * NW + wsub) * NPX + m * PXM + p4;
#pragma unroll
    for (int i = 0; i < 8; ++i) {
      hrA[i] = *(const float4*)(H_re + rb0 + (size_t)i * 8 * NPX);
      hiA[i] = *(const float4*)(H_im + rb0 + (size_t)i * 8 * NPX);
    }
  }
  float ypr_r = 0.f, ypr_i = 0.f, tpr = 0.f;
  if (t < 64) {
    ypr_r = y_re[b * NVIS_ + t];
    ypr_i = y_im[b * NVIS_ + t];
    tpr = 0.f;   // iter 0 uses tpe_=0 (guarded in STEP_BODY)
  }

  for (int iter = 0; iter < niter; ++iter) {
    for (int k = 0; k < NK; k += 2) {
      STEP_BODY(k,     hrA, hiA, hrB, hiB)
      STEP_BODY(k + 1, hrB, hiB, hrA, hiA)
    }

    // ---- global soft-threshold ----
    {
      float ax = 0.f;
      int p = t & 127;
      if (t < PXM) {
        float xr = xs[2 * p], xi = xs[2 * p + 1];
        ax = sqrtf(xr * xr + xi * xi);
        axs[p] = ax;
      }
      __syncthreads();
      for (int off = 64; off > 0; off >>= 1) {
        if (t < off) axs[t] = fmaxf(axs[t], axs[t + off]);
        __syncthreads();
      }
      if (t == 0)
        __hip_atomic_fetch_max(gmax + iter, __float_as_uint(axs[0]),
                               __ATOMIC_RELAXED, __HIP_MEMORY_SCOPE_AGENT);
      gbar_all(root, leaf, 2 + iter);
      float gm = __uint_as_float(__hip_atomic_load(gmax + iter, __ATOMIC_RELAXED,
                                                   __HIP_MEMORY_SCOPE_AGENT));
      if (t < PXM) {
        float mag = fmaxf(ax - thr * gm, 0.f);
        float sc = (ax > 0.f) ? (mag / ax) : 0.f;
        xs[2 * p] *= sc; xs[2 * p + 1] *= sc;
        if (iter == niter - 1) out[b * NPX + m * PXM + p] = mag;
      }
      __syncthreads();
    }
  }
}

extern "C" void kernel_launch(void* const* d_in, const int* in_sizes, int n_in,
                              void* d_out, int out_size, void* d_ws, size_t ws_size,
                              hipStream_t stream) {
  const float* y_re = (const float*)d_in[0];
  const float* y_im = (const float*)d_in[1];
  const float* H_re = (const float*)d_in[2];
  const float* H_im = (const float*)d_in[3];
  const float* Ew   = (const float*)d_in[4];
  const float* Eb   = (const float*)d_in[5];
  const float* Uw   = (const float*)d_in[6];
  const float* Ub   = (const float*)d_in[7];
  const float* Mw   = (const float*)d_in[8];
  const float* Mb   = (const float*)d_in[9];
  const float* thr  = (const float*)d_in[10];
  const int*  niter = (const int*)d_in[11];

  robbi_init<<<1, 256, 0, stream>>>((unsigned*)d_ws);
  robbi_persistent<<<NWG, TPB, 0, stream>>>(
      y_re, y_im, H_re, H_im, Ew, Eb, Uw, Ub, Mw, Mb, thr, niter,
      (float*)d_out, (float*)d_ws);
}

// Round 6
// 59382.294 us; speedup vs baseline: 1.6742x; 1.6742x over previous
//
#include <hip/hip_runtime.h>
#include <math.h>

// Problem constants (fixed by the reference)
#define NB     16       // batch
#define NW     64       // net width W
#define NK     1024     // number of vis blocks
#define NPX    1024     // NPIX
#define NVIS_  65536
#define MEMB   8        // member WGs per batch
#define PXM    128      // pixels per member
#define TPB    256
#define DWIN   4        // Gram window

#define AG_LDF(p)    __hip_atomic_load((p), __ATOMIC_RELAXED, __HIP_MEMORY_SCOPE_AGENT)
#define AG_STF(p,v)  __hip_atomic_store((p), (v), __ATOMIC_RELAXED, __HIP_MEMORY_SCOPE_AGENT)
#define AG_LDU(p)    __hip_atomic_load((p), __ATOMIC_RELAXED, __HIP_MEMORY_SCOPE_AGENT)
#define AG_STU(p,v)  __hip_atomic_store((p), (v), __ATOMIC_RELAXED, __HIP_MEMORY_SCOPE_AGENT)

// ---------------- NEW (pipe) ws layout, 32-bit words ----------------
//   0..2047     : control (gbar root @0, leaves @32*(x+1), gmax @288)
//   2048        : sring [NB][16][MEMB][NW] x {sr,si,seq,pad}   (2 MB)
//   526336      : rring [NB][16][NW] x {rr,ri,seq,pad}         (256 KB)
//   591872      : x0p   [128][NB][PXM][2] f32                  (2 MB)
//   1116160     : tau   [NB][NK][NW] f32                       (4 MB)
//   4194304     : G     [NK][DWIN][64(c)][64(w)] packed bf16   (64 MB)
#define WS2_GMAX    288
#define WS2_SRING_W 2048
#define WS2_RRING_W 526336
#define WS2_X0P_W   591872
#define WS2_TAU_W   1116160
#define WS2_G_W     4194304
#define INIT_W      591872
#define MIN_WS2     ((size_t)(16u << 20) + (size_t)NK * DWIN * 64 * 64 * 4)  // 80 MB

// ---------------- FALLBACK (R4) ws layout ----------------
#define FB_GMAX  288
#define FB_GRP   320
#define FB_PART  1024
#define FB_X0P   36864
#define FB_TAU   589824

__global__ void robbi_init(unsigned* ws) {
  const int n = INIT_W;
  for (int i = blockIdx.x * blockDim.x + threadIdx.x; i < n; i += gridDim.x * blockDim.x)
    __hip_atomic_store(ws + i, 0u, __ATOMIC_RELAXED, __HIP_MEMORY_SCOPE_AGENT);
}

// Global barrier among the 128 member WGs (x0 handoff + per-sweep threshold).
__device__ __forceinline__ void gbar_all(unsigned* root, unsigned* leaf, unsigned n) {
  __syncthreads();
  if (threadIdx.x == 0) {
    unsigned old = __hip_atomic_fetch_add(leaf, 1u, __ATOMIC_ACQ_REL, __HIP_MEMORY_SCOPE_AGENT);
    if ((old & 15u) == 15u)
      __hip_atomic_fetch_add(root, 1u, __ATOMIC_ACQ_REL, __HIP_MEMORY_SCOPE_AGENT);
    const unsigned target = 8u * n;
    while (__hip_atomic_load(root, __ATOMIC_ACQUIRE, __HIP_MEMORY_SCOPE_AGENT) < target)
      __builtin_amdgcn_s_sleep(4);
  }
  __syncthreads();
}

// ==================== Gram kernel: G[j][j+d] = H_j * conj(H_{j+d})^T ====================
__global__ __launch_bounds__(256) void robbi_gram(const float* __restrict__ H_re,
                                                  const float* __restrict__ H_im,
                                                  float* ws) {
  const int j = blockIdx.x >> 2;
  const int d = (blockIdx.x & 3) + 1;
  const int k = j + d;
  if (k >= NK) return;
  unsigned* Gu = (unsigned*)ws + WS2_G_W;
  const int t = threadIdx.x;
  __shared__ float hj[64 * 130];   // [row][px*2], row stride 130 (pad)
  __shared__ float hk[64 * 130];
  const int c = t & 63, wg = t >> 6;
  float accr[16], acci[16];
#pragma unroll
  for (int ii = 0; ii < 16; ++ii) { accr[ii] = 0.f; acci[ii] = 0.f; }
  for (int pc = 0; pc < 16; ++pc) {
    // stage 64px chunk of both row-blocks
    for (int q = t; q < 1024; q += 256) {
      int row = q >> 4, px4 = (q & 15) * 4;
      size_t offj = (size_t)(j * NW + row) * NPX + pc * 64 + px4;
      size_t offk = (size_t)(k * NW + row) * NPX + pc * 64 + px4;
      float4 r4 = *(const float4*)(H_re + offj);
      float4 i4 = *(const float4*)(H_im + offj);
      int b0 = row * 130 + px4 * 2;
      hj[b0 + 0] = r4.x; hj[b0 + 1] = i4.x; hj[b0 + 2] = r4.y; hj[b0 + 3] = i4.y;
      hj[b0 + 4] = r4.z; hj[b0 + 5] = i4.z; hj[b0 + 6] = r4.w; hj[b0 + 7] = i4.w;
      r4 = *(const float4*)(H_re + offk);
      i4 = *(const float4*)(H_im + offk);
      hk[b0 + 0] = r4.x; hk[b0 + 1] = i4.x; hk[b0 + 2] = r4.y; hk[b0 + 3] = i4.y;
      hk[b0 + 4] = r4.z; hk[b0 + 5] = i4.z; hk[b0 + 6] = r4.w; hk[b0 + 7] = i4.w;
    }
    __syncthreads();
#pragma unroll
    for (int ii = 0; ii < 16; ++ii) {
      const int w = wg * 16 + ii;
      float ar_ = 0.f, ai_ = 0.f;
      for (int px = 0; px < 64; ++px) {
        float jr = hj[w * 130 + px * 2], ji = hj[w * 130 + px * 2 + 1];
        float kr = hk[c * 130 + px * 2], ki = hk[c * 130 + px * 2 + 1];
        ar_ += jr * kr + ji * ki;     // Hj * conj(Hk)
        ai_ += ji * kr - jr * ki;
      }
      accr[ii] += ar_; acci[ii] += ai_;
    }
    __syncthreads();
  }
#pragma unroll
  for (int ii = 0; ii < 16; ++ii) {
    unsigned br = __float_as_uint(accr[ii]);
    br = (br + 0x7FFFu + ((br >> 16) & 1u)) & 0xFFFF0000u;        // RNE bf16, hi half
    unsigned bi = __float_as_uint(acci[ii]);
    bi = ((bi + 0x7FFFu + ((bi >> 16) & 1u)) >> 16) & 0xFFFFu;    // RNE bf16, lo half
    Gu[((size_t)(j * DWIN + (d - 1)) * 64 + c) * 64 + wg * 16 + ii] = br | bi;
  }
}

// ==================== main pipelined kernel ====================
// Grid = 144 WGs x 256: bid 0..127 members (b=bid&7 + 8*((bid>>3)>>3), m=(bid>>3)&7),
// bid 128..143 sequencers (b = bid-128).

// --- member: load H tile (64 w x 128 px complex) rows w=8i+wsub, quad p4 ---
#define MLOADT(KIDX, HR, HI)                                                   \
  {                                                                            \
    const size_t rb_ = (size_t)((KIDX) * NW + wsub) * NPX + m * PXM + p4;      \
    _Pragma("unroll")                                                          \
    for (int i = 0; i < 8; ++i) {                                              \
      HR[i] = *(const float4*)(H_re + rb_ + (size_t)i * 8 * NPX);              \
      HI[i] = *(const float4*)(H_im + rb_ + (size_t)i * 8 * NPX);              \
    }                                                                          \
  }

// --- member: phase A (s = x*conj(H_k)) + post to sring slot KSLOT ---
#define MPHASEA(KSLOT, AHR, AHI)                                               \
  {                                                                            \
    const unsigned Ls_ = (unsigned)(iter * NK + (KSLOT));                      \
    float4 xq0_ = *(const float4*)&xs[p4 * 2];                                 \
    float4 xq1_ = *(const float4*)&xs[p4 * 2 + 4];                             \
    float zpr_[8], zpi_[8];                                                    \
    _Pragma("unroll")                                                          \
    for (int i = 0; i < 8; ++i) {                                              \
      float zr_ = xq0_.x * AHR[i].x + xq0_.y * AHI[i].x                        \
                + xq0_.z * AHR[i].y + xq0_.w * AHI[i].y                        \
                + xq1_.x * AHR[i].z + xq1_.y * AHI[i].z                        \
                + xq1_.z * AHR[i].w + xq1_.w * AHI[i].w;                       \
      float zi_ = xq0_.y * AHR[i].x - xq0_.x * AHI[i].x                        \
                + xq0_.w * AHR[i].y - xq0_.z * AHI[i].y                        \
                + xq1_.y * AHR[i].z - xq1_.x * AHI[i].z                        \
                + xq1_.w * AHR[i].w - xq1_.z * AHI[i].w;                       \
      _Pragma("unroll")                                                        \
      for (int msk = 16; msk >= 1; msk >>= 1) {                                \
        zr_ += __shfl_xor(zr_, msk); zi_ += __shfl_xor(zi_, msk);              \
      }                                                                        \
      zpr_[i] = zr_; zpi_[i] = zi_;                                            \
    }                                                                          \
    if (g5 == 0) {                                                             \
      _Pragma("unroll")                                                        \
      for (int i = 0; i < 8; ++i) {                                            \
        unsigned wb_ = WS2_SRING_W +                                           \
          (((b * 16 + (int)(Ls_ & 15u)) * MEMB + m) * NW + 8 * i + wsub) * 4;  \
        AG_STF((float*)(wsu + wb_),     zpr_[i]);                              \
        AG_STF((float*)(wsu + wb_ + 1), zpi_[i]);                              \
      }                                                                        \
    }                                                                          \
    asm volatile("" ::: "memory");                                             \
    asm volatile("s_waitcnt vmcnt(0)" ::: "memory");  /* data before tag */    \
    asm volatile("" ::: "memory");                                             \
    if (g5 == 0) {                                                             \
      _Pragma("unroll")                                                        \
      for (int i = 0; i < 8; ++i) {                                            \
        unsigned wb_ = WS2_SRING_W +                                           \
          (((b * 16 + (int)(Ls_ & 15u)) * MEMB + m) * NW + 8 * i + wsub) * 4;  \
        AG_STU(wsu + wb_ + 2, Ls_ + 1u);                                       \
      }                                                                        \
    }                                                                          \
  }

// --- member: one step j: validate r_j, phase C, phase A(j+1+D), prefetch ---
#define MSTEP(JARG, CHR, CHI, AHR, AHI, CHRn, CHIn, AHRn, AHIn)                \
  {                                                                            \
    const int j_ = (JARG);                                                     \
    const unsigned Lj_ = (unsigned)(iter * NK + j_);                           \
    if (t < 64) {                                                              \
      for (;;) {                                                               \
        if (rpz == Lj_ + 1u) break;                                            \
        unsigned wb_ = WS2_RRING_W + ((b * 16 + (int)(Lj_ & 15u)) * NW + t) * 4; \
        rpx = AG_LDF((float*)(wsu + wb_));                                     \
        rpy = AG_LDF((float*)(wsu + wb_ + 1));                                 \
        rpz = AG_LDU(wsu + wb_ + 2);                                           \
        if (rpz != Lj_ + 1u) __builtin_amdgcn_s_sleep(0);                      \
      }                                                                        \
      rs[2 * t] = rpx; rs[2 * t + 1] = rpy;                                    \
    }                                                                          \
    asm volatile("s_waitcnt lgkmcnt(0)" ::: "memory");                         \
    __builtin_amdgcn_s_barrier();                                              \
    /* phase C: x += (1/W) rs · H_j */                                         \
    {                                                                          \
      float cr0_=0.f,ci0_=0.f,cr1_=0.f,ci1_=0.f,cr2_=0.f,ci2_=0.f,cr3_=0.f,ci3_=0.f; \
      _Pragma("unroll")                                                        \
      for (int i = 0; i < 8; ++i) {                                            \
        float rr_ = rs[(8 * i + wsub) * 2], ri_ = rs[(8 * i + wsub) * 2 + 1];  \
        cr0_ += rr_*CHR[i].x - ri_*CHI[i].x; ci0_ += rr_*CHI[i].x + ri_*CHR[i].x; \
        cr1_ += rr_*CHR[i].y - ri_*CHI[i].y; ci1_ += rr_*CHI[i].y + ri_*CHR[i].y; \
        cr2_ += rr_*CHR[i].z - ri_*CHI[i].z; ci2_ += rr_*CHI[i].z + ri_*CHR[i].z; \
        cr3_ += rr_*CHR[i].w - ri_*CHI[i].w; ci3_ += rr_*CHI[i].w + ri_*CHR[i].w; \
      }                                                                        \
      float4* r8_ = (float4*)red8;                                             \
      r8_[(wsub * 32 + g5) * 2]     = make_float4(cr0_, ci0_, cr1_, ci1_);     \
      r8_[(wsub * 32 + g5) * 2 + 1] = make_float4(cr2_, ci2_, cr3_, ci3_);     \
      asm volatile("s_waitcnt lgkmcnt(0)" ::: "memory");                       \
      __builtin_amdgcn_s_barrier();                                            \
      int p_ = t & 127, c_ = t >> 7;                                           \
      float ssum_ = 0.f;                                                       \
      _Pragma("unroll")                                                        \
      for (int w2 = 0; w2 < 8; ++w2)                                           \
        ssum_ += red8[(w2 * 32 + (p_ >> 2)) * 8 + (p_ & 3) * 2 + c_];          \
      xs[p_ * 2 + c_] += ssum_ * (1.f / NW);                                   \
      asm volatile("s_waitcnt lgkmcnt(0)" ::: "memory");                       \
      __builtin_amdgcn_s_barrier();                                            \
    }                                                                          \
    const int kA_ = j_ + 1 + DWIN;                                             \
    if (kA_ < NK) { MPHASEA(kA_, AHR, AHI) }                                   \
    asm volatile("" ::: "memory");                                             \
    if (j_ + 1 < NK) { MLOADT(j_ + 1, CHRn, CHIn) }                            \
    if (kA_ + 1 < NK) { MLOADT(kA_ + 1, AHRn, AHIn) }                          \
    if (t < 64 && j_ + 1 < NK) {                                               \
      unsigned wb_ = WS2_RRING_W + ((b * 16 + (int)((Lj_ + 1u) & 15u)) * NW + t) * 4; \
      rpx = AG_LDF((float*)(wsu + wb_));                                       \
      rpy = AG_LDF((float*)(wsu + wb_ + 1));                                   \
      rpz = AG_LDU(wsu + wb_ + 2);                                             \
    }                                                                          \
  }

// --- sequencer: 64x64 complex matvec accumulate into zt2[TSL] ---
#define MV1(UU, WW, RSL)                                                       \
  { float2 rl_ = rloc2[(RSL) * 64 + (WW)];                                     \
    float gr_ = __uint_as_float((UU) & 0xffff0000u);                           \
    float gi_ = __uint_as_float((UU) << 16);                                   \
    accr_ += rl_.x * gr_ - rl_.y * gi_;                                        \
    acci_ += rl_.x * gi_ + rl_.y * gr_; }

#define SEQ_MV(GQ, RSL, TSL)                                                   \
  { float accr_ = 0.f, acci_ = 0.f;                                            \
    _Pragma("unroll")                                                          \
    for (int q_ = 0; q_ < 16; ++q_) {                                          \
      uint4 u_ = GQ[q_];                                                       \
      MV1(u_.x, 4 * q_ + 0, RSL) MV1(u_.y, 4 * q_ + 1, RSL)                    \
      MV1(u_.z, 4 * q_ + 2, RSL) MV1(u_.w, 4 * q_ + 3, RSL)                    \
    }                                                                          \
    float2 z_ = zt2[(TSL) * 64 + lane];                                        \
    z_.x += accr_ * (1.f / NW); z_.y += acci_ * (1.f / NW);                    \
    zt2[(TSL) * 64 + lane] = z_; }

#define SEQ_GLOAD(GQ, KJ, DD)                                                  \
  { const uint4* gp_ = (const uint4*)(Gu + ((size_t)((KJ) * DWIN + ((DD) - 1)) * 64 + lane) * 64); \
    _Pragma("unroll")                                                          \
    for (int q_ = 0; q_ < 16; ++q_) GQ[q_] = gp_[q_]; }

__global__ __launch_bounds__(TPB, 1) void robbi_pipe(
    const float* __restrict__ y_re, const float* __restrict__ y_im,
    const float* __restrict__ H_re, const float* __restrict__ H_im,
    const float* __restrict__ Ew, const float* __restrict__ Eb,
    const float* __restrict__ Uw, const float* __restrict__ Ub,
    const float* __restrict__ Mw, const float* __restrict__ Mb,
    const float* __restrict__ thr_p, const int* __restrict__ niter_p,
    float* __restrict__ out, float* ws) {
  const int bid = blockIdx.x;
  const int t = threadIdx.x;
  unsigned* wsu  = (unsigned*)ws;
  unsigned* root = wsu;
  unsigned* gmax = wsu + WS2_GMAX;
  float* x0p = ws + WS2_X0P_W;
  float* tau = ws + WS2_TAU_W;
  const unsigned* Gu = wsu + WS2_G_W;

  // member LDS
  __shared__ float xs[PXM * 2];
  __shared__ float rs[2 * NW];
  __shared__ float red8[2048];
  __shared__ float ysr[2048], ysi[2048];
  __shared__ float axs[PXM];
  // sequencer LDS
  __shared__ float swE[NW * 65], swU[NW * 65], swM[NW * 65];
  __shared__ float sbE[NW], sbU[NW], sbM[NW];
  __shared__ float2 zt2[16 * 64];
  __shared__ float2 rloc2[16 * 64];
  __shared__ float r2s[NW], tpl[NW], hts[NW];

  const float thr = *thr_p;
  const int niter = *niter_p;

  if (bid >= 128) {
    // ==================== SEQUENCER (batch b) ====================
    const int b = bid - 128;
    const int wv = t >> 6, lane = t & 63;
    // weights
    for (int i = t; i < NW * NW; i += TPB) {
      int r = i >> 6, c = i & 63;
      swE[r * 65 + c] = Ew[i]; swU[r * 65 + c] = Uw[i]; swM[r * 65 + c] = Mw[i];
    }
    if (t < NW) { sbE[t] = Eb[t]; sbU[t] = Ub[t]; sbM[t] = Mb[t]; }
    for (int i = t; i < 16 * 64; i += TPB) zt2[i] = make_float2(0.f, 0.f);
    __syncthreads();
    if (niter <= 0) return;

    float ypr = 0.f, ypi = 0.f, tpr = 0.f;
    float ssx[MEMB], ssy[MEMB];
    unsigned ssz[MEMB];
    uint4 gq[16];
#pragma unroll
    for (int mm = 0; mm < MEMB; ++mm) { ssx[mm] = 0.f; ssy[mm] = 0.f; ssz[mm] = 0u; }
#pragma unroll
    for (int q = 0; q < 16; ++q) gq[q] = make_uint4(0u, 0u, 0u, 0u);

    if (wv == 0) {
      ypr = y_re[b * NVIS_ + lane];
      ypi = y_im[b * NVIS_ + lane];
      tpr = 0.f;
#pragma unroll
      for (int mm = 0; mm < MEMB; ++mm) {
        unsigned wb = WS2_SRING_W + ((b * 16 + 0) * MEMB + mm) * NW * 4 + lane * 4;
        ssx[mm] = AG_LDF((float*)(wsu + wb));
        ssy[mm] = AG_LDF((float*)(wsu + wb + 1));
        ssz[mm] = AG_LDU(wsu + wb + 2);
      }
    }

    const int NTOT = niter * NK;
    for (int LL = 0; LL < NTOT; ++LL) {
      const int k = LL & (NK - 1);
      const int it_ = LL >> 10;
      const int kk1 = k - 1;
      // ---------- phase 1 ----------
      if (wv == 0) {
        const unsigned seqw = (unsigned)LL + 1u;
        for (;;) {
          bool ok = true;
#pragma unroll
          for (int mm = 0; mm < MEMB; ++mm) ok = ok && (ssz[mm] == seqw);
          if (ok) break;
#pragma unroll
          for (int mm = 0; mm < MEMB; ++mm) {
            unsigned wb = WS2_SRING_W +
              (((b * 16 + (LL & 15)) * MEMB + mm) * NW + lane) * 4;
            ssx[mm] = AG_LDF((float*)(wsu + wb));
            ssy[mm] = AG_LDF((float*)(wsu + wb + 1));
            ssz[mm] = AG_LDU(wsu + wb + 2);
          }
          __builtin_amdgcn_s_sleep(0);
        }
        if (kk1 >= 0 && kk1 + 4 < NK) { SEQ_MV(gq, (LL - 1) & 15, (LL - 1 + 4) & 15) }
      } else {
        const int d_ = wv;
        if (kk1 >= 0 && kk1 + d_ < NK) { SEQ_MV(gq, (LL - 1) & 15, (LL - 1 + d_) & 15) }
      }
      asm volatile("s_waitcnt lgkmcnt(0)" ::: "memory");
      __builtin_amdgcn_s_barrier();
      // ---------- phase 2 ----------
      if (wv == 0) {
        float2 zt_ = zt2[(LL & 15) * 64 + lane];
        float zr = zt_.x, zi = zt_.y;
#pragma unroll
        for (int mm = 0; mm < MEMB; ++mm) { zr += ssx[mm]; zi += ssy[mm]; }
        zt2[(LL & 15) * 64 + lane] = make_float2(0.f, 0.f);
        float dr = ypr - zr, di = ypi - zi;
        r2s[lane] = dr * dr + di * di;
        tpl[lane] = (it_ == 0) ? 0.f : tpr;
        asm volatile("s_waitcnt lgkmcnt(0)" ::: "memory");
        float e = sbE[lane];
#pragma unroll 16
        for (int jj = 0; jj < 64; ++jj) e += swE[lane * 65 + jj] * r2s[jj];
        hts[lane] = 1.f / (1.f + __expf(-e));
        asm volatile("s_waitcnt lgkmcnt(0)" ::: "memory");
        float a = sbU[lane] + sbM[lane];
#pragma unroll 16
        for (int jj = 0; jj < 64; ++jj)
          a += swU[lane * 65 + jj] * hts[jj] + swM[lane * 65 + jj] * tpl[jj];
        float wn = fmaxf(a, 0.f);
        tau[(size_t)(b * NK + k) * NW + lane] = wn;
        float rr = ypr - zr * wn, ri = ypi - zi * wn;
        rloc2[(LL & 15) * 64 + lane] = make_float2(rr, ri);
        unsigned wb = WS2_RRING_W + ((b * 16 + (LL & 15)) * NW + lane) * 4;
        AG_STF((float*)(wsu + wb), rr);
        AG_STF((float*)(wsu + wb + 1), ri);
        asm volatile("" ::: "memory");
        asm volatile("s_waitcnt vmcnt(0)" ::: "memory");
        asm volatile("" ::: "memory");
        AG_STU(wsu + wb + 2, (unsigned)LL + 1u);
        if (LL + 1 < NTOT) {
          const int k2 = (LL + 1) & (NK - 1);
          ypr = y_re[b * NVIS_ + k2 * NW + lane];
          ypi = y_im[b * NVIS_ + k2 * NW + lane];
          tpr = tau[(size_t)(b * NK + k2) * NW + lane];
#pragma unroll
          for (int mm = 0; mm < MEMB; ++mm) {
            unsigned wb2 = WS2_SRING_W +
              (((b * 16 + ((LL + 1) & 15)) * MEMB + mm) * NW + lane) * 4;
            ssx[mm] = AG_LDF((float*)(wsu + wb2));
            ssy[mm] = AG_LDF((float*)(wsu + wb2 + 1));
            ssz[mm] = AG_LDU(wsu + wb2 + 2);
          }
          if (k + 4 < NK) { SEQ_GLOAD(gq, k, 4) }
        }
      } else {
        const int d_ = wv;
        if (k + d_ < NK && LL + 1 < NTOT) { SEQ_GLOAD(gq, k, d_) }
      }
      asm volatile("s_waitcnt lgkmcnt(0)" ::: "memory");
      __builtin_amdgcn_s_barrier();
    }
    return;
  }

  // ==================== MEMBER ====================
  const int xcd = bid & 7, gi = bid >> 3;
  const int b = xcd + 8 * (gi >> 3);   // batch 0..15
  const int m = gi & 7;                // member 0..7
  unsigned* leaf = wsu + 32 * (xcd + 1);

  const int wsub = t >> 5;        // 0..7
  const int g5   = t & 31;        // 0..31
  const int p4   = 4 * g5;        // pixel quad base in 128-px slice

  // ---- x0 stage 1 (non-redundant partial GEMM) ----
  {
    const int kwc = bid >> 3, ps = bid & 7;
    float ar[2][4], ai[2][4];
#pragma unroll
    for (int h = 0; h < 2; ++h)
#pragma unroll
      for (int j = 0; j < 4; ++j) { ar[h][j] = 0.f; ai[h][j] = 0.f; }
    for (int slab = 0; slab < 32; ++slab) {
      const int kw0 = kwc * 4096 + slab * 128;
      for (int e = t; e < 2048; e += TPB) {
        int bb = e >> 7, j = e & 127;
        ysr[e] = y_re[bb * NVIS_ + kw0 + j];
        ysi[e] = y_im[bb * NVIS_ + kw0 + j];
      }
      __syncthreads();
      for (int j = 0; j < 128; ++j) {
        const size_t off = (size_t)(kw0 + j) * NPX + ps * PXM + p4;
        float4 h4r = *(const float4*)(H_re + off);
        float4 h4i = *(const float4*)(H_im + off);
#pragma unroll
        for (int h = 0; h < 2; ++h) {
          int bb = wsub + 8 * h;
          float yr = ysr[bb * 128 + j], yi = ysi[bb * 128 + j];
          ar[h][0] += yr * h4r.x - yi * h4i.x; ai[h][0] += yr * h4i.x + yi * h4r.x;
          ar[h][1] += yr * h4r.y - yi * h4i.y; ai[h][1] += yr * h4i.y + yi * h4r.y;
          ar[h][2] += yr * h4r.z - yi * h4i.z; ai[h][2] += yr * h4i.z + yi * h4r.z;
          ar[h][3] += yr * h4r.w - yi * h4i.w; ai[h][3] += yr * h4i.w + yi * h4r.w;
        }
      }
      __syncthreads();
    }
#pragma unroll
    for (int h = 0; h < 2; ++h) {
      int bb = wsub + 8 * h;
#pragma unroll
      for (int j = 0; j < 4; ++j) {
        float* pp = x0p + ((size_t)(bid * NB + bb) * PXM + p4 + j) * 2;
        AG_STF(pp, ar[h][j]); AG_STF(pp + 1, ai[h][j]);
      }
    }
  }
  gbar_all(root, leaf, 1);
  {
    int p = t & 127, c = t >> 7;
    float s = 0.f;
    for (int kwc = 0; kwc < 16; ++kwc)
      s += AG_LDF(x0p + ((size_t)((kwc * 8 + m) * NB + b) * PXM + p) * 2 + c);
    xs[p * 2 + c] = s;
  }
  __syncthreads();

  if (niter <= 0) {
    if (t < PXM) {
      float xr = xs[2 * t], xi = xs[2 * t + 1];
      out[b * NPX + m * PXM + t] = sqrtf(xr * xr + xi * xi);
    }
    return;
  }

  float4 hCra[8], hCia[8], hCrb[8], hCib[8];
  float4 hAra[8], hAia[8], hArb[8], hAib[8];
  float rpx = 0.f, rpy = 0.f;
  unsigned rpz = 0u;

  for (int iter = 0; iter < niter; ++iter) {
    // ---- sweep prologue: post s slots 0..DWIN from x_0 ----
    for (int kk = 0; kk <= DWIN; ++kk) {
      MLOADT(kk, hAra, hAia)
      MPHASEA(kk, hAra, hAia)
    }
    // preload main-loop tiles + r prefetch for j=0
    MLOADT(0, hCra, hCia)
    MLOADT(DWIN + 1, hAra, hAia)
    if (t < 64) {
      unsigned wb_ = WS2_RRING_W + ((b * 16 + (int)(((unsigned)(iter * NK)) & 15u)) * NW + t) * 4;
      rpx = AG_LDF((float*)(wsu + wb_));
      rpy = AG_LDF((float*)(wsu + wb_ + 1));
      rpz = AG_LDU(wsu + wb_ + 2);
    }
    for (int j = 0; j < NK; j += 2) {
      MSTEP(j,     hCra, hCia, hAra, hAia, hCrb, hCib, hArb, hAib)
      MSTEP(j + 1, hCrb, hCib, hArb, hAib, hCra, hCia, hAra, hAia)
    }
    // ---- global soft-threshold ----
    {
      float ax = 0.f;
      int p = t & 127;
      if (t < PXM) {
        float xr = xs[2 * p], xi = xs[2 * p + 1];
        ax = sqrtf(xr * xr + xi * xi);
        axs[p] = ax;
      }
      __syncthreads();
      for (int off = 64; off > 0; off >>= 1) {
        if (t < off) axs[t] = fmaxf(axs[t], axs[t + off]);
        __syncthreads();
      }
      if (t == 0)
        __hip_atomic_fetch_max(gmax + iter, __float_as_uint(axs[0]),
                               __ATOMIC_RELAXED, __HIP_MEMORY_SCOPE_AGENT);
      gbar_all(root, leaf, 2 + iter);
      float gm = __uint_as_float(__hip_atomic_load(gmax + iter, __ATOMIC_RELAXED,
                                                   __HIP_MEMORY_SCOPE_AGENT));
      if (t < PXM) {
        float mag = fmaxf(ax - thr * gm, 0.f);
        float sc = (ax > 0.f) ? (mag / ax) : 0.f;
        xs[2 * p] *= sc; xs[2 * p + 1] *= sc;
        if (iter == niter - 1) out[b * NPX + m * PXM + p] = mag;
      }
      __syncthreads();
    }
  }
}

// ==================== R4 fallback (proven 75 ms) ====================
#define STEP_FB(KARG, HRC, HIC, HRN, HIN)                                      \
  {                                                                            \
    const int k_ = (KARG);                                                     \
    const int buf_ = k_ & 1;                                                   \
    float4 xq0_ = *(const float4*)&xs[p4 * 2];                                 \
    float4 xq1_ = *(const float4*)&xs[p4 * 2 + 4];                             \
    float zpr_[8], zpi_[8];                                                    \
    _Pragma("unroll")                                                          \
    for (int i = 0; i < 8; ++i) {                                              \
      float zr = xq0_.x * HRC[i].x + xq0_.y * HIC[i].x                         \
               + xq0_.z * HRC[i].y + xq0_.w * HIC[i].y                         \
               + xq1_.x * HRC[i].z + xq1_.y * HIC[i].z                         \
               + xq1_.z * HRC[i].w + xq1_.w * HIC[i].w;                        \
      float zi = xq0_.y * HRC[i].x - xq0_.x * HIC[i].x                         \
               + xq0_.w * HRC[i].y - xq0_.z * HIC[i].y                         \
               + xq1_.y * HRC[i].z - xq1_.x * HIC[i].z                         \
               + xq1_.w * HRC[i].w - xq1_.z * HIC[i].w;                        \
      _Pragma("unroll")                                                        \
      for (int msk = 16; msk >= 1; msk >>= 1) {                                \
        zr += __shfl_xor(zr, msk); zi += __shfl_xor(zi, msk);                  \
      }                                                                        \
      zpr_[i] = zr; zpi_[i] = zi;                                              \
    }                                                                          \
    if (g5 == 0) {                                                             \
      _Pragma("unroll")                                                        \
      for (int i = 0; i < 8; ++i) {                                            \
        float* pp = part + (size_t)(((buf_ * NB + b) * MEMB + m) * NW + 8 * i + wsub) * 2; \
        AG_STF(pp, zpr_[i]); AG_STF(pp + 1, zpi_[i]);                          \
      }                                                                        \
    }                                                                          \
    asm volatile("" ::: "memory");                                             \
    {                                                                          \
      const int kn_ = (k_ + 1 < NK) ? (k_ + 1) : 0;                            \
      const size_t rbn_ = (size_t)(kn_ * NW + wsub) * NPX + m * PXM + p4;      \
      _Pragma("unroll")                                                        \
      for (int i = 0; i < 8; ++i) {                                            \
        HRN[i] = *(const float4*)(H_re + rbn_ + (size_t)i * 8 * NPX);          \
        HIN[i] = *(const float4*)(H_im + rbn_ + (size_t)i * 8 * NPX);          \
      }                                                                        \
    }                                                                          \
    asm volatile("s_waitcnt vmcnt(16)" ::: "memory");                          \
    __builtin_amdgcn_s_barrier();                                              \
    if (t == 0) {                                                              \
      __hip_atomic_fetch_add(grpc, 1u, __ATOMIC_RELAXED, __HIP_MEMORY_SCOPE_AGENT); \
      const unsigned tgt_ = 8u * (unsigned)(iter * NK + k_ + 1);               \
      while (__hip_atomic_load(grpc, __ATOMIC_ACQUIRE, __HIP_MEMORY_SCOPE_AGENT) < tgt_) \
        __builtin_amdgcn_s_sleep(1);                                           \
    }                                                                          \
    __builtin_amdgcn_s_barrier();                                              \
    if (t < 64) {                                                              \
      float zr = 0.f, zi = 0.f;                                                \
      _Pragma("unroll")                                                        \
      for (int mm = 0; mm < MEMB; ++mm) {                                      \
        const float* pp = part + (size_t)(((buf_ * NB + b) * MEMB + mm) * NW + t) * 2; \
        zr += AG_LDF(pp); zi += AG_LDF(pp + 1);                                \
      }                                                                        \
      float tpe = (iter == 0) ? 0.f : tpr;                                     \
      float dr = ypr_r - zr, di = ypr_i - zi;                                  \
      r2s[t] = dr * dr + di * di;                                              \
      tpl[t] = tpe;                                                            \
      float e = sbE[t];                                                        \
      _Pragma("unroll 16")                                                     \
      for (int j = 0; j < 64; ++j) e += swE[t * 65 + j] * r2s[j];              \
      hts[t] = 1.f / (1.f + __expf(-e));                                       \
      float a = sbU[t] + sbM[t];                                               \
      _Pragma("unroll 16")                                                     \
      for (int j = 0; j < 64; ++j)                                             \
        a += swU[t * 65 + j] * hts[j] + swM[t * 65 + j] * tpl[j];              \
      float wn = fmaxf(a, 0.f);                                                \
      if (m == 0) AG_STF(tau + (size_t)(b * NK + k_) * NW + t, wn);            \
      rs[2 * t] = ypr_r - zr * wn; rs[2 * t + 1] = ypr_i - zi * wn;            \
      const int kn_ = (k_ + 1 < NK) ? (k_ + 1) : 0;                            \
      ypr_r = y_re[b * NVIS_ + kn_ * NW + t];                                  \
      ypr_i = y_im[b * NVIS_ + kn_ * NW + t];                                  \
      tpr = AG_LDF(tau + (size_t)(b * NK + kn_) * NW + t);                     \
    }                                                                          \
    asm volatile("s_waitcnt lgkmcnt(0)" ::: "memory");                         \
    __builtin_amdgcn_s_barrier();                                              \
    {                                                                          \
      float cr0=0.f,ci0=0.f,cr1=0.f,ci1=0.f,cr2=0.f,ci2=0.f,cr3=0.f,ci3=0.f;   \
      _Pragma("unroll")                                                        \
      for (int i = 0; i < 8; ++i) {                                            \
        float rr = rs[(8 * i + wsub) * 2], ri = rs[(8 * i + wsub) * 2 + 1];    \
        cr0 += rr * HRC[i].x - ri * HIC[i].x; ci0 += rr * HIC[i].x + ri * HRC[i].x; \
        cr1 += rr * HRC[i].y - ri * HIC[i].y; ci1 += rr * HIC[i].y + ri * HRC[i].y; \
        cr2 += rr * HRC[i].z - ri * HIC[i].z; ci2 += rr * HIC[i].z + ri * HRC[i].z; \
        cr3 += rr * HRC[i].w - ri * HIC[i].w; ci3 += rr * HIC[i].w + ri * HRC[i].w; \
      }                                                                        \
      float4* r8_ = (float4*)red8;                                             \
      r8_[(wsub * 32 + g5) * 2]     = make_float4(cr0, ci0, cr1, ci1);         \
      r8_[(wsub * 32 + g5) * 2 + 1] = make_float4(cr2, ci2, cr3, ci3);         \
      asm volatile("s_waitcnt lgkmcnt(0)" ::: "memory");                       \
      __builtin_amdgcn_s_barrier();                                            \
      int p_ = t & 127, c_ = t >> 7;                                           \
      float ssum = 0.f;                                                        \
      _Pragma("unroll")                                                        \
      for (int w2 = 0; w2 < 8; ++w2)                                           \
        ssum += red8[(w2 * 32 + (p_ >> 2)) * 8 + (p_ & 3) * 2 + c_];           \
      xs[p_ * 2 + c_] += ssum * (1.f / NW);                                    \
      asm volatile("s_waitcnt lgkmcnt(0)" ::: "memory");                       \
      __builtin_amdgcn_s_barrier();                                            \
    }                                                                          \
  }

__global__ __launch_bounds__(TPB) void robbi_fb(
    const float* __restrict__ y_re, const float* __restrict__ y_im,
    const float* __restrict__ H_re, const float* __restrict__ H_im,
    const float* __restrict__ Ew, const float* __restrict__ Eb,
    const float* __restrict__ Uw, const float* __restrict__ Ub,
    const float* __restrict__ Mw, const float* __restrict__ Mb,
    const float* __restrict__ thr_p, const int* __restrict__ niter_p,
    float* __restrict__ out, float* ws) {
  const int bid = blockIdx.x;
  const int t = threadIdx.x;
  const int xcd = bid & 7, gi = bid >> 3;
  const int b = xcd + 8 * (gi >> 3);
  const int m = gi & 7;

  unsigned* wsu  = (unsigned*)ws;
  unsigned* root = wsu;
  unsigned* leaf = wsu + 32 * (xcd + 1);
  unsigned* gmax = wsu + FB_GMAX;
  unsigned* grpc = wsu + FB_GRP + 32 * b;
  float* part = ws + FB_PART;
  float* x0p  = ws + FB_X0P;
  float* tau  = ws + FB_TAU;

  __shared__ float swE[NW * 65], swU[NW * 65], swM[NW * 65];
  __shared__ float sbE[NW], sbU[NW], sbM[NW];
  __shared__ float xs[PXM * 2];
  __shared__ float r2s[NW], tpl[NW], hts[NW];
  __shared__ float rs[2 * NW];
  __shared__ float red8[2048];
  __shared__ float ysr[2048], ysi[2048];
  __shared__ float axs[PXM];

  const float thr = *thr_p;
  const int niter = *niter_p;

  for (int i = t; i < NW * NW; i += TPB) {
    int r = i >> 6, c = i & 63;
    swE[r * 65 + c] = Ew[i]; swU[r * 65 + c] = Uw[i]; swM[r * 65 + c] = Mw[i];
  }
  if (t < NW) { sbE[t] = Eb[t]; sbU[t] = Ub[t]; sbM[t] = Mb[t]; }

  const int wsub = t >> 5;
  const int g5   = t & 31;
  const int p4   = 4 * g5;

  {
    const int kwc = bid >> 3, ps = bid & 7;
    float ar[2][4], ai[2][4];
#pragma unroll
    for (int h = 0; h < 2; ++h)
#pragma unroll
      for (int j = 0; j < 4; ++j) { ar[h][j] = 0.f; ai[h][j] = 0.f; }
    for (int slab = 0; slab < 32; ++slab) {
      const int kw0 = kwc * 4096 + slab * 128;
      for (int e = t; e < 2048; e += TPB) {
        int bb = e >> 7, j = e & 127;
        ysr[e] = y_re[bb * NVIS_ + kw0 + j];
        ysi[e] = y_im[bb * NVIS_ + kw0 + j];
      }
      __syncthreads();
      for (int j = 0; j < 128; ++j) {
        const size_t off = (size_t)(kw0 + j) * NPX + ps * PXM + p4;
        float4 h4r = *(const float4*)(H_re + off);
        float4 h4i = *(const float4*)(H_im + off);
#pragma unroll
        for (int h = 0; h < 2; ++h) {
          int bb = wsub + 8 * h;
          float yr = ysr[bb * 128 + j], yi = ysi[bb * 128 + j];
          ar[h][0] += yr * h4r.x - yi * h4i.x; ai[h][0] += yr * h4i.x + yi * h4r.x;
          ar[h][1] += yr * h4r.y - yi * h4i.y; ai[h][1] += yr * h4i.y + yi * h4r.y;
          ar[h][2] += yr * h4r.z - yi * h4i.z; ai[h][2] += yr * h4i.z + yi * h4r.z;
          ar[h][3] += yr * h4r.w - yi * h4i.w; ai[h][3] += yr * h4i.w + yi * h4r.w;
        }
      }
      __syncthreads();
    }
#pragma unroll
    for (int h = 0; h < 2; ++h) {
      int bb = wsub + 8 * h;
#pragma unroll
      for (int j = 0; j < 4; ++j) {
        float* pp = x0p + ((size_t)(bid * NB + bb) * PXM + p4 + j) * 2;
        AG_STF(pp, ar[h][j]); AG_STF(pp + 1, ai[h][j]);
      }
    }
  }
  gbar_all(root, leaf, 1);
  {
    int p = t & 127, c = t >> 7;
    float s = 0.f;
    for (int kwc = 0; kwc < 16; ++kwc)
      s += AG_LDF(x0p + ((size_t)((kwc * 8 + m) * NB + b) * PXM + p) * 2 + c);
    xs[p * 2 + c] = s;
  }
  __syncthreads();

  if (niter <= 0) {
    if (t < PXM) {
      float xr = xs[2 * t], xi = xs[2 * t + 1];
      out[b * NPX + m * PXM + t] = sqrtf(xr * xr + xi * xi);
    }
    return;
  }

  float4 hrA[8], hiA[8], hrB[8], hiB[8];
  {
    const size_t rb0 = (size_t)(0 * NW + wsub) * NPX + m * PXM + p4;
#pragma unroll
    for (int i = 0; i < 8; ++i) {
      hrA[i] = *(const float4*)(H_re + rb0 + (size_t)i * 8 * NPX);
      hiA[i] = *(const float4*)(H_im + rb0 + (size_t)i * 8 * NPX);
    }
  }
  float ypr_r = 0.f, ypr_i = 0.f, tpr = 0.f;
  if (t < 64) {
    ypr_r = y_re[b * NVIS_ + t];
    ypr_i = y_im[b * NVIS_ + t];
  }

  for (int iter = 0; iter < niter; ++iter) {
    for (int k = 0; k < NK; k += 2) {
      STEP_FB(k,     hrA, hiA, hrB, hiB)
      STEP_FB(k + 1, hrB, hiB, hrA, hiA)
    }
    {
      float ax = 0.f;
      int p = t & 127;
      if (t < PXM) {
        float xr = xs[2 * p], xi = xs[2 * p + 1];
        ax = sqrtf(xr * xr + xi * xi);
        axs[p] = ax;
      }
      __syncthreads();
      for (int off = 64; off > 0; off >>= 1) {
        if (t < off) axs[t] = fmaxf(axs[t], axs[t + off]);
        __syncthreads();
      }
      if (t == 0)
        __hip_atomic_fetch_max(gmax + iter, __float_as_uint(axs[0]),
                               __ATOMIC_RELAXED, __HIP_MEMORY_SCOPE_AGENT);
      gbar_all(root, leaf, 2 + iter);
      float gm = __uint_as_float(__hip_atomic_load(gmax + iter, __ATOMIC_RELAXED,
                                                   __HIP_MEMORY_SCOPE_AGENT));
      if (t < PXM) {
        float mag = fmaxf(ax - thr * gm, 0.f);
        float sc = (ax > 0.f) ? (mag / ax) : 0.f;
        xs[2 * p] *= sc; xs[2 * p + 1] *= sc;
        if (iter == niter - 1) out[b * NPX + m * PXM + p] = mag;
      }
      __syncthreads();
    }
  }
}

extern "C" void kernel_launch(void* const* d_in, const int* in_sizes, int n_in,
                              void* d_out, int out_size, void* d_ws, size_t ws_size,
                              hipStream_t stream) {
  const float* y_re = (const float*)d_in[0];
  const float* y_im = (const float*)d_in[1];
  const float* H_re = (const float*)d_in[2];
  const float* H_im = (const float*)d_in[3];
  const float* Ew   = (const float*)d_in[4];
  const float* Eb   = (const float*)d_in[5];
  const float* Uw   = (const float*)d_in[6];
  const float* Ub   = (const float*)d_in[7];
  const float* Mw   = (const float*)d_in[8];
  const float* Mb   = (const float*)d_in[9];
  const float* thr  = (const float*)d_in[10];
  const int*  niter = (const int*)d_in[11];

  robbi_init<<<256, 256, 0, stream>>>((unsigned*)d_ws);
  if (ws_size >= MIN_WS2) {
    robbi_gram<<<NK * DWIN, 256, 0, stream>>>(H_re, H_im, (float*)d_ws);
    robbi_pipe<<<144, TPB, 0, stream>>>(
        y_re, y_im, H_re, H_im, Ew, Eb, Uw, Ub, Mw, Mb, thr, niter,
        (float*)d_out, (float*)d_ws);
  } else {
    robbi_fb<<<128, TPB, 0, stream>>>(
        y_re, y_im, H_re, H_im, Ew, Eb, Uw, Ub, Mw, Mb, thr, niter,
        (float*)d_out, (float*)d_ws);
  }
}

// Round 7
// 55806.897 us; speedup vs baseline: 1.7814x; 1.0641x over previous
//
#include <hip/hip_runtime.h>
#include <math.h>

// Problem constants
#define NB     16
#define NW     64
#define NK     1024
#define NPX    1024
#define NVIS_  65536
#define NMEM   15        // member WGs per batch
#define TPB    256
#define NWG    256       // 240 members + 16 sequencers
#define NQP    19        // padded quad stride (max 18 quads = 72 px)

// ws word offsets
#define WS_ROOTA   0
#define WS_ROOTB   16
#define WS_GMAX    288        // 64 slots
#define WS_SRING_W 2048       // [16 b][8 slot][15 m][64 w] x 16B  (491,520 w)
#define WS_RRING_W 493568     // [16 b][8 slot][64 w] x 16B        (32,768 w)
#define WS_X0P_W   526336     // [32 kwc][16 b][1024 px][2] f32    (1,048,576 w)
#define WS_TAU_W   1574912    // [16 b][1024 k][64 w] f32          (1,048,576 w)
#define WS_G_W     2623488    // [1024 j][2 d][64 c][64 w] u32 bf16pair (8,388,608 w)
#define INIT_W     526336

#define AG_LDF(p)    __hip_atomic_load((p), __ATOMIC_RELAXED, __HIP_MEMORY_SCOPE_AGENT)
#define AG_STF(p,v)  __hip_atomic_store((p), (v), __ATOMIC_RELAXED, __HIP_MEMORY_SCOPE_AGENT)
#define AG_STU(p,v)  __hip_atomic_store((p), (v), __ATOMIC_RELAXED, __HIP_MEMORY_SCOPE_AGENT)
#define AG_ST64(p,v) __hip_atomic_store((p), (v), __ATOMIC_RELAXED, __HIP_MEMORY_SCOPE_AGENT)

#define BARL() do { asm volatile("s_waitcnt lgkmcnt(0)" ::: "memory"); \
                    __builtin_amdgcn_s_barrier(); } while (0)

typedef struct { float re[NW][NQP][4]; float im[NW][NQP][4]; } HTile;   // 38,912 B
typedef struct {
  HTile tile[3];          // rolling C-tiles (slot = k % 3)
  float xs[160];          // x slice (<=72 px * 2), padded
  float rs[128];          // r[w] re/im
  float partl[128];       // A-phase partials handoff to wave0
  float red[8][NQP][8];   // C-phase cross-wave reduction
  float axs[128];
} MemSM;                  // ~123.8 KB
typedef struct {
  float wE[NW*65], wU[NW*65], wM[NW*65];
  float bE[NW], bU[NW], bM[NW];
  float ztA[128], ztB[128];
  float rloc[2][128];
  float rpost[128];
  float r2s[NW], tpl[NW], hts[NW];
} SeqSM;
typedef struct { float ysr[2048], ysi[2048]; } X0SM;
typedef union { MemSM m; SeqSM q; X0SM x; } SMem;

__global__ void robbi_init(unsigned* ws) {
  for (int i = blockIdx.x * blockDim.x + threadIdx.x; i < INIT_W; i += gridDim.x * blockDim.x)
    __hip_atomic_store(ws + i, 0u, __ATOMIC_RELAXED, __HIP_MEMORY_SCOPE_AGENT);
}

__device__ __forceinline__ void gbar(unsigned* root, unsigned* leaf, int leafmod, unsigned ntarget) {
  __syncthreads();
  if (threadIdx.x == 0) {
    unsigned old = __hip_atomic_fetch_add(leaf, 1u, __ATOMIC_ACQ_REL, __HIP_MEMORY_SCOPE_AGENT);
    if ((old % (unsigned)leafmod) == (unsigned)(leafmod - 1))
      __hip_atomic_fetch_add(root, 1u, __ATOMIC_ACQ_REL, __HIP_MEMORY_SCOPE_AGENT);
    while (__hip_atomic_load(root, __ATOMIC_ACQUIRE, __HIP_MEMORY_SCOPE_AGENT) < ntarget)
      __builtin_amdgcn_s_sleep(4);
  }
  __syncthreads();
}

// ---- Gram: G[j][d][c][w] = H_j[w] . conj(H_{j+d})[c], packed bf16 {re_hi, im_lo} ----
__global__ __launch_bounds__(256) void robbi_gram(const float* __restrict__ H_re,
                                                  const float* __restrict__ H_im,
                                                  float* ws) {
  const int j = blockIdx.x >> 1;
  const int d = (blockIdx.x & 1) + 1;
  const int k = j + d;
  if (k >= NK) return;
  unsigned* Gu = (unsigned*)ws + WS_G_W;
  const int t = threadIdx.x;
  __shared__ float hj[64 * 130];
  __shared__ float hk[64 * 130];
  const int c = t & 63, wg = t >> 6;
  float accr[16], acci[16];
#pragma unroll
  for (int ii = 0; ii < 16; ++ii) { accr[ii] = 0.f; acci[ii] = 0.f; }
  for (int pc = 0; pc < 16; ++pc) {
    for (int q = t; q < 1024; q += 256) {
      int row = q >> 4, px4 = (q & 15) * 4;
      size_t offj = (size_t)(j * NW + row) * NPX + pc * 64 + px4;
      size_t offk = (size_t)(k * NW + row) * NPX + pc * 64 + px4;
      float4 r4 = *(const float4*)(H_re + offj);
      float4 i4 = *(const float4*)(H_im + offj);
      int b0 = row * 130 + px4 * 2;
      hj[b0+0]=r4.x; hj[b0+1]=i4.x; hj[b0+2]=r4.y; hj[b0+3]=i4.y;
      hj[b0+4]=r4.z; hj[b0+5]=i4.z; hj[b0+6]=r4.w; hj[b0+7]=i4.w;
      r4 = *(const float4*)(H_re + offk);
      i4 = *(const float4*)(H_im + offk);
      hk[b0+0]=r4.x; hk[b0+1]=i4.x; hk[b0+2]=r4.y; hk[b0+3]=i4.y;
      hk[b0+4]=r4.z; hk[b0+5]=i4.z; hk[b0+6]=r4.w; hk[b0+7]=i4.w;
    }
    __syncthreads();
#pragma unroll
    for (int ii = 0; ii < 16; ++ii) {
      const int w = wg * 16 + ii;
      float ar_ = 0.f, ai_ = 0.f;
      for (int px = 0; px < 64; ++px) {
        float jr = hj[w*130 + px*2], ji = hj[w*130 + px*2 + 1];
        float kr = hk[c*130 + px*2], ki = hk[c*130 + px*2 + 1];
        ar_ += jr*kr + ji*ki;
        ai_ += ji*kr - jr*ki;
      }
      accr[ii] += ar_; acci[ii] += ai_;
    }
    __syncthreads();
  }
#pragma unroll
  for (int ii = 0; ii < 16; ++ii) {
    unsigned br = __float_as_uint(accr[ii]);
    br = (br + 0x7FFFu + ((br >> 16) & 1u)) & 0xFFFF0000u;
    unsigned bi = __float_as_uint(acci[ii]);
    bi = ((bi + 0x7FFFu + ((bi >> 16) & 1u)) >> 16) & 0xFFFFu;
    Gu[((size_t)(j * 2 + (d - 1)) * 64 + c) * 64 + wg * 16 + ii] = br | bi;
  }
}

#define GMAC(UU, IDX)                                                           \
  { unsigned uu_ = (UU);                                                        \
    float gr_ = __uint_as_float(uu_ & 0xffff0000u);                             \
    float gi_ = __uint_as_float(uu_ << 16);                                     \
    float rr_ = rl[2*(IDX)], ri_ = rl[2*(IDX)+1];                               \
    ar += rr_*gr_ - ri_*gi_; ai += rr_*gi_ + ri_*gr_; }

__global__ __launch_bounds__(TPB, 1) void robbi_pipe(
    const float* __restrict__ y_re, const float* __restrict__ y_im,
    const float* __restrict__ H_re, const float* __restrict__ H_im,
    const float* __restrict__ Ew, const float* __restrict__ Eb,
    const float* __restrict__ Uw, const float* __restrict__ Ub,
    const float* __restrict__ Mw, const float* __restrict__ Mb,
    const float* __restrict__ thr_p, const int* __restrict__ niter_p,
    float* __restrict__ out, float* ws) {
  const int bid = blockIdx.x;
  const int t = threadIdx.x;
  unsigned* wsu = (unsigned*)ws;
  const unsigned* Gu = wsu + WS_G_W;
  float* tau = ws + WS_TAU_W;
  __shared__ SMem sm;

  const float thr = *thr_p;
  const int niter = *niter_p;
  const int wsub = t >> 5;
  const int g5 = t & 31;
  const int p4 = 4 * g5;

  // ================= x0 stage 1: all 256 WGs (kwc = bid>>3, ps = bid&7) =================
  {
    const int kwc = bid >> 3, ps = bid & 7;
    float ar[2][4], ai[2][4];
#pragma unroll
    for (int h = 0; h < 2; ++h)
#pragma unroll
      for (int j = 0; j < 4; ++j) { ar[h][j] = 0.f; ai[h][j] = 0.f; }
    for (int slab = 0; slab < 16; ++slab) {
      const int kw0 = kwc * 2048 + slab * 128;
      for (int e = t; e < 2048; e += TPB) {
        int bb = e >> 7, j = e & 127;
        sm.x.ysr[e] = y_re[bb * NVIS_ + kw0 + j];
        sm.x.ysi[e] = y_im[bb * NVIS_ + kw0 + j];
      }
      __syncthreads();
      for (int j = 0; j < 128; ++j) {
        const size_t off2 = (size_t)(kw0 + j) * NPX + ps * 128 + p4;
        float4 h4r = *(const float4*)(H_re + off2);
        float4 h4i = *(const float4*)(H_im + off2);
#pragma unroll
        for (int h = 0; h < 2; ++h) {
          int bb = wsub + 8 * h;
          float yr = sm.x.ysr[bb * 128 + j], yi = sm.x.ysi[bb * 128 + j];
          ar[h][0] += yr*h4r.x - yi*h4i.x; ai[h][0] += yr*h4i.x + yi*h4r.x;
          ar[h][1] += yr*h4r.y - yi*h4i.y; ai[h][1] += yr*h4i.y + yi*h4r.y;
          ar[h][2] += yr*h4r.z - yi*h4i.z; ai[h][2] += yr*h4i.z + yi*h4r.z;
          ar[h][3] += yr*h4r.w - yi*h4i.w; ai[h][3] += yr*h4i.w + yi*h4r.w;
        }
      }
      __syncthreads();
    }
#pragma unroll
    for (int h = 0; h < 2; ++h) {
      int bb = wsub + 8 * h;
#pragma unroll
      for (int j = 0; j < 4; ++j) {
        float* pp = ws + WS_X0P_W + ((size_t)((kwc * NB + bb) * NPX + ps * 128 + p4 + j)) * 2;
        AG_STF(pp, ar[h][j]); AG_STF(pp + 1, ai[h][j]);
      }
    }
  }
  gbar(wsu + WS_ROOTA, wsu + 32 * (1 + (bid & 7)), 32, 8u);

  // ================================== SEQUENCER ==================================
  if (bid >= NB * NMEM) {
    const int b = bid - NB * NMEM;
    SeqSM* Q = &sm.q;
    for (int i = t; i < NW * NW; i += TPB) {
      int r = i >> 6, c = i & 63;
      Q->wE[r*65+c] = Ew[i]; Q->wU[r*65+c] = Uw[i]; Q->wM[r*65+c] = Mw[i];
    }
    if (t < NW) { Q->bE[t] = Eb[t]; Q->bU[t] = Ub[t]; Q->bM[t] = Mb[t]; }
    __syncthreads();
    if (niter <= 0) return;

    const int lane = t & 63;
    float ypr = 0.f, ypi = 0.f, tpr = 0.f;
    if (t < 64) { ypr = y_re[b * NVIS_ + t]; ypi = y_im[b * NVIS_ + t]; }
    uint4 g1[16], g2[16];
#pragma unroll
    for (int q2 = 0; q2 < 16; ++q2) { g1[q2] = make_uint4(0,0,0,0); g2[q2] = make_uint4(0,0,0,0); }

    const long NTOT = (long)niter * NK;
    for (long L = 0; L < NTOT; ++L) {
      const int k = (int)(L & (NK - 1));
      const int it2 = (int)(L >> 10);
      float zr = 0.f, zi = 0.f;
      // ---------------- phase 1 ----------------
      if (t < 64) {
        // wave0: poll all 15 member s-entries (16B snapshot loads, sc-coherent)
        const unsigned want = (unsigned)L + 1u;
        const int slot8 = (int)(L & 7);
        for (;;) {
          uint4 u[NMEM];
#pragma unroll
          for (int m2 = 0; m2 < NMEM; ++m2) {
            const uint4* p = (const uint4*)(wsu + WS_SRING_W +
              ((size_t)((b * 8 + slot8) * NMEM + m2) * 64 + t) * 4);
            asm volatile("global_load_dwordx4 %0, %1, off sc0 sc1" : "=v"(u[m2]) : "v"(p));
          }
          asm volatile("s_waitcnt vmcnt(0)" ::: "memory");
          __builtin_amdgcn_sched_barrier(0);
          bool ok = true; float ar = 0.f, ai = 0.f;
#pragma unroll
          for (int m2 = 0; m2 < NMEM; ++m2) {
            ok = ok && (u[m2].z == want);
            ar += __uint_as_float(u[m2].x); ai += __uint_as_float(u[m2].y);
          }
          if (__all((int)ok)) { zr = ar; zi = ai; break; }
          __builtin_amdgcn_s_sleep(1);
        }
      } else if (t < 128) {           // wave1: correction d=1 for target k
        if (k >= 1) {
          const float* rl = Q->rloc[(int)((L - 1) & 1)];
          float ar = 0.f, ai = 0.f;
#pragma unroll
          for (int q2 = 0; q2 < 16; ++q2) {
            uint4 u = g1[q2];
            GMAC(u.x, 4*q2+0) GMAC(u.y, 4*q2+1) GMAC(u.z, 4*q2+2) GMAC(u.w, 4*q2+3)
          }
          Q->ztA[2*lane] = ar * (1.f / NW); Q->ztA[2*lane+1] = ai * (1.f / NW);
        }
      } else if (t < 192) {           // wave2: correction d=2 for target k
        if (k >= 2) {
          const float* rl = Q->rloc[(int)((L - 2) & 1)];
          float ar = 0.f, ai = 0.f;
#pragma unroll
          for (int q2 = 0; q2 < 16; ++q2) {
            uint4 u = g2[q2];
            GMAC(u.x, 4*q2+0) GMAC(u.y, 4*q2+1) GMAC(u.z, 4*q2+2) GMAC(u.w, 4*q2+3)
          }
          Q->ztB[2*lane] = ar * (1.f / NW); Q->ztB[2*lane+1] = ai * (1.f / NW);
        }
      } else {                        // wave3: post r_{k-1}
        if (k >= 1) {
          const unsigned Lr = (unsigned)(L - 1);
          union { float2 f2; unsigned long long u; } cv;
          cv.f2 = make_float2(Q->rpost[2*lane], Q->rpost[2*lane+1]);
          unsigned woff = WS_RRING_W + (((b * 8 + (int)(Lr & 7u)) * 64 + lane)) * 4;
          AG_ST64((unsigned long long*)(wsu + woff), cv.u);
          asm volatile("s_waitcnt vmcnt(0)" ::: "memory");
          AG_STU(wsu + woff + 2, Lr + 1u);
        }
      }
      BARL();
      // ---------------- phase 2 ----------------
      if (t < 64) {
        float z_r = zr, z_i = zi;
        if (k >= 1) { z_r += Q->ztA[2*t]; z_i += Q->ztA[2*t+1]; }
        if (k >= 2) { z_r += Q->ztB[2*t]; z_i += Q->ztB[2*t+1]; }
        float dr = ypr - z_r, di = ypi - z_i;
        Q->r2s[t] = dr*dr + di*di;
        Q->tpl[t] = (it2 == 0) ? 0.f : tpr;
        asm volatile("s_waitcnt lgkmcnt(0)" ::: "memory");
        float e = Q->bE[t];
#pragma unroll 16
        for (int j2 = 0; j2 < 64; ++j2) e += Q->wE[t*65+j2] * Q->r2s[j2];
        Q->hts[t] = 1.f / (1.f + __expf(-e));
        asm volatile("s_waitcnt lgkmcnt(0)" ::: "memory");
        float a = Q->bU[t] + Q->bM[t];
#pragma unroll 16
        for (int j2 = 0; j2 < 64; ++j2)
          a += Q->wU[t*65+j2] * Q->hts[j2] + Q->wM[t*65+j2] * Q->tpl[j2];
        float wn = fmaxf(a, 0.f);
        tau[((size_t)b * NK + k) * NW + t] = wn;
        float rr = ypr - z_r * wn, ri = ypi - z_i * wn;
        Q->rloc[(int)(L & 1)][2*t] = rr; Q->rloc[(int)(L & 1)][2*t+1] = ri;
        Q->rpost[2*t] = rr; Q->rpost[2*t+1] = ri;
        if (L + 1 < NTOT) {
          const int k2 = (int)((L + 1) & (NK - 1));
          ypr = y_re[b * NVIS_ + k2 * NW + t];
          ypi = y_im[b * NVIS_ + k2 * NW + t];
          tpr = tau[((size_t)b * NK + k2) * NW + t];
        }
      } else if (t < 128) {           // wave1: prefetch G for target k+1, d=1 (j'=k)
        if (k + 1 < NK) {
          const unsigned* gp = Gu + ((size_t)(k * 2 + 0) * 64 + lane) * 64;
#pragma unroll
          for (int q2 = 0; q2 < 16; ++q2) g1[q2] = ((const uint4*)gp)[q2];
        }
      } else if (t < 192) {           // wave2: prefetch G for target k+1, d=2 (j'=k-1)
        if (k + 1 < NK && k >= 1) {
          const unsigned* gp = Gu + ((size_t)((k - 1) * 2 + 1) * 64 + lane) * 64;
#pragma unroll
          for (int q2 = 0; q2 < 16; ++q2) g2[q2] = ((const uint4*)gp)[q2];
        }
      }
      BARL();
      // sweep boundary: wave3 posts r_{NK-1} (members need it before the threshold)
      if (k == NK - 1 && t >= 192) {
        union { float2 f2; unsigned long long u; } cv;
        cv.f2 = make_float2(Q->rpost[2*lane], Q->rpost[2*lane+1]);
        unsigned woff = WS_RRING_W + (((b * 8 + (int)(L & 7u)) * 64 + lane)) * 4;
        AG_ST64((unsigned long long*)(wsu + woff), cv.u);
        asm volatile("s_waitcnt vmcnt(0)" ::: "memory");
        AG_STU(wsu + woff + 2, (unsigned)L + 1u);
      }
    }
    return;
  }

  // ================================== MEMBER ==================================
  const int b = bid / NMEM;
  const int m = bid % NMEM;
  const int off = m * 68;
  const int cnt = (m == NMEM - 1) ? 72 : 68;
  const int nq = cnt >> 2;
  MemSM* M = &sm.m;

  // x0 stage 2: reduce 32 kw-chunks into xs
  if (t < cnt * 2) {
    int p = t >> 1, c = t & 1;
    float s = 0.f;
    for (int kwc = 0; kwc < 32; ++kwc)
      s += AG_LDF(ws + WS_X0P_W + ((size_t)((kwc * NB + b) * NPX + off + p)) * 2 + c);
    M->xs[2 * p + c] = s;
  }
  __syncthreads();

  if (niter <= 0) {
    if (t < cnt) {
      float xr = M->xs[2*t], xi = M->xs[2*t+1];
      out[b * NPX + off + t] = sqrtf(xr*xr + xi*xi);
    }
    return;
  }

  float4 hr[8], hi[8];

  auto load_tile = [&](int k) {
    if (g5 < nq) {
      const size_t rb = ((size_t)k * NW + wsub) * NPX + off + p4;
#pragma unroll
      for (int i = 0; i < 8; ++i) {
        hr[i] = *(const float4*)(H_re + rb + (size_t)i * 8 * NPX);
        hi[i] = *(const float4*)(H_im + rb + (size_t)i * 8 * NPX);
      }
    }
  };
  auto store_tile = [&](int slot) {
    if (g5 < nq) {
#pragma unroll
      for (int i = 0; i < 8; ++i) {
        int w = 8 * i + wsub;
        *(float4*)&M->tile[slot].re[w][g5][0] = hr[i];
        *(float4*)&M->tile[slot].im[w][g5][0] = hi[i];
      }
    }
  };
  auto compute_A = [&]() {   // s = x . conj(H): partials -> shuffle -> partl
    float zpr[8], zpi[8];
    float4 xq0 = make_float4(0,0,0,0), xq1 = make_float4(0,0,0,0);
    if (g5 < nq) { xq0 = *(const float4*)&M->xs[p4*2]; xq1 = *(const float4*)&M->xs[p4*2+4]; }
#pragma unroll
    for (int i = 0; i < 8; ++i) {
      float zr = 0.f, zi = 0.f;
      if (g5 < nq) {
        zr = xq0.x*hr[i].x + xq0.y*hi[i].x + xq0.z*hr[i].y + xq0.w*hi[i].y
           + xq1.x*hr[i].z + xq1.y*hi[i].z + xq1.z*hr[i].w + xq1.w*hi[i].w;
        zi = xq0.y*hr[i].x - xq0.x*hi[i].x + xq0.w*hr[i].y - xq0.z*hi[i].y
           + xq1.y*hr[i].z - xq1.x*hi[i].z + xq1.w*hr[i].w - xq1.z*hi[i].w;
      }
#pragma unroll
      for (int msk = 16; msk >= 1; msk >>= 1) {
        zr += __shfl_xor(zr, msk); zi += __shfl_xor(zi, msk);
      }
      zpr[i] = zr; zpi[i] = zi;
    }
    if (g5 == 0) {
#pragma unroll
      for (int i = 0; i < 8; ++i) {
        M->partl[(8*i + wsub)*2]     = zpr[i];
        M->partl[(8*i + wsub)*2 + 1] = zpi[i];
      }
    }
  };
  auto post_s = [&](unsigned Ls) {   // wave0 (t<64) only
    const int slot8 = (int)(Ls & 7u);
    union { float2 f2; unsigned long long u; } cv;
    cv.f2 = make_float2(M->partl[2*t], M->partl[2*t+1]);
    unsigned woff = WS_SRING_W + ((size_t)((b * 8 + slot8) * NMEM + m) * 64 + t) * 4;
    AG_ST64((unsigned long long*)(wsu + woff), cv.u);
    asm volatile("s_waitcnt vmcnt(0)" ::: "memory");
    AG_STU(wsu + woff + 2, Ls + 1u);
  };
  auto poll_r = [&](unsigned Lr) {   // wave1 (t in [64,128)) only; lane = t-64
    const int l = t - 64;
    const unsigned want = Lr + 1u;
    const uint4* p = (const uint4*)(wsu + WS_RRING_W +
        ((size_t)((b * 8 + (int)(Lr & 7u)) * 64 + l)) * 4);
    uint4 u;
    for (;;) {
      asm volatile("global_load_dwordx4 %0, %1, off sc0 sc1\n\ts_waitcnt vmcnt(0)"
                   : "=v"(u) : "v"(p) : "memory");
      if (__all((int)(u.z == want))) break;
      __builtin_amdgcn_s_sleep(1);
    }
    M->rs[2*l]   = __uint_as_float(u.x);
    M->rs[2*l+1] = __uint_as_float(u.y);
  };

  for (int iter = 0; iter < niter; ++iter) {
    const unsigned L0 = (unsigned)(iter * NK);
    // ---- prologue: post s_0..s_2 from x_start; fill LDS slots 0..2; tile 3 in regs ----
    for (int kk = 0; kk < 3; ++kk) {
      load_tile(kk);
      compute_A();
      BARL();
      if (t < 64) post_s(L0 + kk);
      store_tile(kk);
      BARL();
    }
    load_tile(3);
    if (t >= 64 && t < 128) poll_r(L0);
    BARL();

    // ---- main loop ----
    for (int j = 0; j < NK; ++j) {
      const int slot = j % 3;
      // phase C: x += (1/W) r_j . H_j  (tile from LDS)
      if (g5 < nq) {
        float dre[4] = {0,0,0,0}, dim[4] = {0,0,0,0};
#pragma unroll
        for (int i = 0; i < 8; ++i) {
          int w = 8*i + wsub;
          float rr = M->rs[2*w], ri = M->rs[2*w+1];
          float4 re4 = *(const float4*)&M->tile[slot].re[w][g5][0];
          float4 im4 = *(const float4*)&M->tile[slot].im[w][g5][0];
          dre[0] += rr*re4.x - ri*im4.x; dim[0] += rr*im4.x + ri*re4.x;
          dre[1] += rr*re4.y - ri*im4.y; dim[1] += rr*im4.y + ri*re4.y;
          dre[2] += rr*re4.z - ri*im4.z; dim[2] += rr*im4.z + ri*re4.z;
          dre[3] += rr*re4.w - ri*im4.w; dim[3] += rr*im4.w + ri*re4.w;
        }
#pragma unroll
        for (int e = 0; e < 4; ++e) {
          M->red[wsub][g5][2*e]   = dre[e];
          M->red[wsub][g5][2*e+1] = dim[e];
        }
      }
      BARL();
      if (t < cnt * 2) {
        int p = t >> 1, c = t & 1;
        float s = 0.f;
#pragma unroll
        for (int u2 = 0; u2 < 8; ++u2) s += M->red[u2][p >> 2][(p & 3) * 2 + c];
        M->xs[2*p + c] += s * (1.f / NW);
      }
      BARL();
      // phase A for k = j+3 (tile in regs)
      const int ka = j + 3;
      if (ka < NK) compute_A();
      BARL();
      if (ka < NK) {
        if (t < 64) post_s(L0 + (unsigned)ka);
        store_tile(slot);              // tile j+3 -> slot (j+3)%3 == j%3 (freed by C)
      }
      if (ka + 1 < NK) load_tile(ka + 1);
      if (j + 1 < NK) { if (t >= 64 && t < 128) poll_r(L0 + (unsigned)(j + 1)); }
      BARL();
    }

    // ---- global soft-threshold (members only) ----
    {
      float ax = 0.f;
      if (t < cnt) {
        float xr = M->xs[2*t], xi = M->xs[2*t+1];
        ax = sqrtf(xr*xr + xi*xi);
        M->axs[t] = ax;
      } else if (t < 128) M->axs[t] = 0.f;
      __syncthreads();
      for (int o = 64; o > 0; o >>= 1) {
        if (t < o) M->axs[t] = fmaxf(M->axs[t], M->axs[t + o]);
        __syncthreads();
      }
      if (t == 0)
        __hip_atomic_fetch_max(wsu + WS_GMAX + (iter & 63), __float_as_uint(M->axs[0]),
                               __ATOMIC_RELAXED, __HIP_MEMORY_SCOPE_AGENT);
      gbar(wsu + WS_ROOTB, wsu + 512 + 32 * (bid & 7), 30, 8u * (unsigned)(iter + 1));
      float gm = __uint_as_float(__hip_atomic_load(wsu + WS_GMAX + (iter & 63),
                                 __ATOMIC_RELAXED, __HIP_MEMORY_SCOPE_AGENT));
      if (t < cnt) {
        float mag = fmaxf(ax - thr * gm, 0.f);
        float sc = (ax > 0.f) ? (mag / ax) : 0.f;
        M->xs[2*t] *= sc; M->xs[2*t+1] *= sc;
        if (iter == niter - 1) out[b * NPX + off + t] = mag;
      }
      __syncthreads();
    }
  }
}

extern "C" void kernel_launch(void* const* d_in, const int* in_sizes, int n_in,
                              void* d_out, int out_size, void* d_ws, size_t ws_size,
                              hipStream_t stream) {
  const float* y_re = (const float*)d_in[0];
  const float* y_im = (const float*)d_in[1];
  const float* H_re = (const float*)d_in[2];
  const float* H_im = (const float*)d_in[3];
  const float* Ew   = (const float*)d_in[4];
  const float* Eb   = (const float*)d_in[5];
  const float* Uw   = (const float*)d_in[6];
  const float* Ub   = (const float*)d_in[7];
  const float* Mw   = (const float*)d_in[8];
  const float* Mb   = (const float*)d_in[9];
  const float* thr  = (const float*)d_in[10];
  const int*  niter = (const int*)d_in[11];
  (void)in_sizes; (void)n_in; (void)out_size; (void)ws_size;

  robbi_init<<<512, 256, 0, stream>>>((unsigned*)d_ws);
  robbi_gram<<<NK * 2, 256, 0, stream>>>(H_re, H_im, (float*)d_ws);
  robbi_pipe<<<NWG, TPB, 0, stream>>>(
      y_re, y_im, H_re, H_im, Ew, Eb, Uw, Ub, Mw, Mb, thr, niter,
      (float*)d_out, (float*)d_ws);
}